// Round 7
// baseline (775.753 us; speedup 1.0000x reference)
//
#include <hip/hip_runtime.h>

// MoEUT time-series decoder, round 7.
// - attn_nolds: flash attention with NO staging LDS and NO barriers.
//   K-frags + V^T-frags direct from global; only P goes through a
//   wave-private LDS slab. Each wave owns 16 Q-rows over all S.
// - QKV GEMM epilogue writes q,k -> [token][2048] and v -> vT[d][token]
//   (packed b64 stores) so attention needs no V transpose.
// - w1 folded to one N=2048 GEMM (gate = col-expert scale in epilogue).
// - mfma_gemm: dbuf LDS, one barrier per K-iter (round-6 win, kept).

#define LNUM 3
#define D 1024
#define H 16
#define HD 64
#define E 8
#define EH 256
#define B 2
#define S 1024
#define DIN 32
#define NOUT 8
#define EPS 1e-5f
#define TOK (B * S)

typedef __bf16 bf16x8 __attribute__((ext_vector_type(8)));
typedef __bf16 bf16x4 __attribute__((ext_vector_type(4)));
typedef float fx4 __attribute__((ext_vector_type(4)));

// ---------------- reductions ----------------
__device__ inline float block_reduce_sum256(float v, float* scratch) {
  int lane = threadIdx.x & 63, wv = threadIdx.x >> 6;
#pragma unroll
  for (int off = 32; off; off >>= 1) v += __shfl_down(v, off);
  __syncthreads();
  if (lane == 0) scratch[wv] = v;
  __syncthreads();
  return scratch[0] + scratch[1] + scratch[2] + scratch[3];
}

// ---------------- LayerNorm -> bf16 ----------------
__global__ __launch_bounds__(256) void ln_bf_kernel(
    const float* __restrict__ in, const float* __restrict__ g,
    const float* __restrict__ bta, __bf16* __restrict__ outb) {
  int token = blockIdx.x;
  int tid = threadIdx.x;
  const float* p = in + (size_t)token * D;
  __shared__ float scratch[4];
  float x[4];
  float s = 0.f, sq = 0.f;
#pragma unroll
  for (int i = 0; i < 4; i++) {
    x[i] = p[tid + i * 256];
    s += x[i];
    sq += x[i] * x[i];
  }
  s = block_reduce_sum256(s, scratch);
  sq = block_reduce_sum256(sq, scratch);
  float mean = s * (1.f / D);
  float inv = rsqrtf(sq * (1.f / D) - mean * mean + EPS);
  __bf16* obp = outb + (size_t)token * D;
#pragma unroll
  for (int i = 0; i < 4; i++) {
    int d = tid + i * 256;
    obp[d] = (__bf16)((x[i] - mean) * inv * g[d] + bta[d]);
  }
}

// ---------------- LayerNorm + sigmoid gate top-2 (fused) ----------------
__global__ __launch_bounds__(256) void ln_gate_kernel(
    const float* __restrict__ in, const float* __restrict__ g,
    const float* __restrict__ bta, const float* __restrict__ selw,
    __bf16* __restrict__ outb, float* __restrict__ gm) {
  int token = blockIdx.x;
  int tid = threadIdx.x;
  const float* p = in + (size_t)token * D;
  __shared__ float scratch[4];
  float x[4];
  float s = 0.f, sq = 0.f;
#pragma unroll
  for (int i = 0; i < 4; i++) {
    x[i] = p[tid + i * 256];
    s += x[i];
    sq += x[i] * x[i];
  }
  s = block_reduce_sum256(s, scratch);
  sq = block_reduce_sum256(sq, scratch);
  float mean = s * (1.f / D);
  float inv = rsqrtf(sq * (1.f / D) - mean * mean + EPS);
  __bf16* obp = outb + (size_t)token * D;
  float ge[E];
#pragma unroll
  for (int e = 0; e < E; e++) ge[e] = 0.f;
#pragma unroll
  for (int i = 0; i < 4; i++) {
    int d = tid + i * 256;
    float y = (x[i] - mean) * inv * g[d] + bta[d];
    obp[d] = (__bf16)y;
#pragma unroll
    for (int e = 0; e < E; e++) ge[e] += y * selw[d * E + e];
  }
  __shared__ float red[4][E];
  int lane = tid & 63, wv = tid >> 6;
#pragma unroll
  for (int e = 0; e < E; e++) {
    float vv = ge[e];
#pragma unroll
    for (int off = 32; off; off >>= 1) vv += __shfl_down(vv, off);
    if (lane == 0) red[wv][e] = vv;
  }
  __syncthreads();
  if (tid == 0) {
    float gg[E];
    for (int e = 0; e < E; e++) {
      float sv = red[0][e] + red[1][e] + red[2][e] + red[3][e];
      gg[e] = 1.f / (1.f + __expf(-sv));
    }
    int i0 = 0;
    for (int e = 1; e < E; e++)
      if (gg[e] > gg[i0]) i0 = e;
    int i1 = -1;
    for (int e = 0; e < E; e++) {
      if (e == i0) continue;
      if (i1 < 0 || gg[e] > gg[i1]) i1 = e;
    }
    float mm[E];
    for (int e = 0; e < E; e++) mm[e] = 0.f;
    mm[i0] = gg[i0];
    mm[i1] = gg[i1];
    for (int e = 0; e < E; e++) gm[(size_t)token * E + e] = mm[e];
  }
}

// ---------------- fp32 tiled GEMM (input projection, K=32) ----------
#define BM 64
#define BKT 16
__global__ __launch_bounds__(256) void gemm_kernel(
    const float* __restrict__ A, const float* __restrict__ Bw,
    const float* __restrict__ bias, float* __restrict__ C, int M, int N,
    int Kd) {
  __shared__ float As[BKT][BM + 1];
  __shared__ float Bs[BKT][BM + 1];
  int bm = blockIdx.y * BM, bn = blockIdx.x * BM;
  int tid = threadIdx.x;
  int tx = tid & 15, ty = tid >> 4;
  float acc[4][4] = {};
  for (int k0 = 0; k0 < Kd; k0 += BKT) {
#pragma unroll
    for (int j = 0; j < 4; j++) {
      int i = tid + j * 256;
      int r = i >> 4, c = i & 15;
      As[c][r] = A[(size_t)(bm + r) * Kd + k0 + c];
    }
#pragma unroll
    for (int j = 0; j < 4; j++) {
      int i = tid + j * 256;
      int n = i >> 4, c = i & 15;
      Bs[c][n] = Bw[(size_t)(bn + n) * Kd + k0 + c];
    }
    __syncthreads();
#pragma unroll
    for (int kk = 0; kk < BKT; kk++) {
      float a[4], bb[4];
#pragma unroll
      for (int i2 = 0; i2 < 4; i2++) a[i2] = As[kk][ty * 4 + i2];
#pragma unroll
      for (int i2 = 0; i2 < 4; i2++) bb[i2] = Bs[kk][tx * 4 + i2];
#pragma unroll
      for (int i2 = 0; i2 < 4; i2++)
#pragma unroll
        for (int j2 = 0; j2 < 4; j2++) acc[i2][j2] += a[i2] * bb[j2];
    }
    __syncthreads();
  }
#pragma unroll
  for (int i2 = 0; i2 < 4; i2++) {
    int row = bm + ty * 4 + i2;
#pragma unroll
    for (int j2 = 0; j2 < 4; j2++) {
      int col = bn + tx * 4 + j2;
      C[(size_t)row * N + col] = acc[i2][j2] + bias[col];
    }
  }
}

// ---------------- bf16 MFMA GEMM, 64xBN, BK=32, dbuf, 1 barrier/iter -----
// C[M,N] = epi(A[M,K] @ Bt[N,K]^T).
// vT!=null (QKV fold): blocks with bn>=2048 write v transposed to
//   vT[(col-2048)*TOK + row] (packed bf16x4 over 4 consecutive rows).
// gateScale!=null (w1 fold): scale by gateScale[row*E + (col>>8)].
// rope!=0: RoPE on (col%64, +32) pairs (q,k cols < 2048).
template <int NI>
__global__ __launch_bounds__(256) void mfma_gemm(
    const __bf16* __restrict__ A, int lda, const __bf16* __restrict__ Bt,
    const float* __restrict__ bias, float* __restrict__ C,
    __bf16* __restrict__ Cbf, int ldc, __bf16* __restrict__ vT,
    const float* __restrict__ gateScale, int K, int accum, int relu,
    int rope) {
  constexpr int BN = NI * 32;
  __shared__ __bf16 As[2][64 * 32];
  __shared__ __bf16 Bs[2][BN * 32];
  int bm = blockIdx.y * 64, bn = blockIdx.x * BN;
  int tid = threadIdx.x, lane = tid & 63, wv = tid >> 6;
  int wr = wv >> 1, wc = wv & 1;
  int half = lane >> 4, mrow = lane & 15;
  const __bf16* Ab = A + (size_t)bm * lda;
  const __bf16* Bb = Bt + (size_t)bn * K;
  fx4 acc[2][NI] = {};
  int aslot[2], bslot[NI];
#pragma unroll
  for (int i = 0; i < 2; i++) {
    int row = wr * 32 + i * 16 + mrow;
    aslot[i] = row * 4 + (half ^ ((row >> 1) & 3));
  }
#pragma unroll
  for (int j = 0; j < NI; j++) {
    int row = wc * (NI * 16) + j * 16 + mrow;
    bslot[j] = row * 4 + (half ^ ((row >> 1) & 3));
  }
  int rowa = tid >> 2, kca = (((tid & 3) ^ ((rowa >> 1) & 3)) << 3);

  auto stage = [&](int buf, int k0) {
    __builtin_amdgcn_global_load_lds(
        (const __attribute__((address_space(1))) void*)(Ab +
                                                        (size_t)rowa * lda +
                                                        k0 + kca),
        (__attribute__((address_space(3))) void*)(&As[buf][tid * 8]), 16, 0, 0);
#pragma unroll
    for (int it = 0; it < NI / 2; it++) {
      int c = tid + it * 256;
      int row = c >> 2;
      int kc = (((c & 3) ^ ((row >> 1) & 3)) << 3);
      __builtin_amdgcn_global_load_lds(
          (const __attribute__((address_space(1))) void*)(Bb + (size_t)row * K +
                                                          k0 + kc),
          (__attribute__((address_space(3))) void*)(&Bs[buf][c * 8]), 16, 0, 0);
    }
  };
  stage(0, 0);
  for (int k0 = 0; k0 < K; k0 += 32) {
    int cur = (k0 >> 5) & 1;
    __syncthreads();
    if (k0 + 32 < K) stage(cur ^ 1, k0 + 32);
    bf16x8 af[2], bfr[NI];
#pragma unroll
    for (int i = 0; i < 2; i++)
      af[i] = *(const bf16x8*)(&As[cur][aslot[i] * 8]);
#pragma unroll
    for (int j = 0; j < NI; j++)
      bfr[j] = *(const bf16x8*)(&Bs[cur][bslot[j] * 8]);
#pragma unroll
    for (int i = 0; i < 2; i++)
#pragma unroll
      for (int j = 0; j < NI; j++)
        acc[i][j] = __builtin_amdgcn_mfma_f32_16x16x32_bf16(af[i], bfr[j],
                                                            acc[i][j], 0, 0, 0);
  }
  if (vT && bn >= 2048) {
    // v block: write transposed, packed over 4 consecutive rows
#pragma unroll
    for (int i = 0; i < 2; i++) {
      int row0 = bm + wr * 32 + i * 16 + half * 4;
#pragma unroll
      for (int j = 0; j < NI; j++) {
        int col = bn + wc * (NI * 16) + j * 16 + mrow;
        float bb = bias ? bias[col] : 0.f;
        bf16x4 pk;
#pragma unroll
        for (int r = 0; r < 4; r++) pk[r] = (__bf16)(acc[i][j][r] + bb);
        *(bf16x4*)(vT + (size_t)(col - 2048) * TOK + row0) = pk;
      }
    }
    return;
  }
#pragma unroll
  for (int i = 0; i < 2; i++) {
#pragma unroll
    for (int r = 0; r < 4; r++) {
      int row = bm + wr * 32 + i * 16 + half * 4 + r;
      float vv[NI];
#pragma unroll
      for (int j = 0; j < NI; j++) {
        int col = bn + wc * (NI * 16) + j * 16 + mrow;
        float val = acc[i][j][r];
        if (bias) val += bias[col];
        if (relu) val = fmaxf(val, 0.f);
        if (gateScale) val *= gateScale[(size_t)row * E + (col >> 8)];
        vv[j] = val;
      }
      if (rope && NI == 4) {
        int spos = row & (S - 1);
#pragma unroll
        for (int jj = 0; jj < 2; jj++) {
          int hd = jj * 16 + mrow;  // 0..31
          float invf = exp2f(hd * -0.4152410118609825f);
          float ang = (float)spos * invf;
          float sn, cs;
          __sincosf(ang, &sn, &cs);
          float a0 = vv[jj], a1 = vv[jj + 2];
          vv[jj] = a0 * cs - a1 * sn;
          vv[jj + 2] = a1 * cs + a0 * sn;
        }
      }
#pragma unroll
      for (int j = 0; j < NI; j++) {
        int col = bn + wc * (NI * 16) + j * 16 + mrow;
        size_t addr = (size_t)row * ldc + col;
        if (Cbf)
          Cbf[addr] = (__bf16)vv[j];
        else if (accum)
          C[addr] += vv[j];
        else
          C[addr] = vv[j];
      }
    }
  }
}

// ---------------- fp32 -> bf16 transpose+convert (z-split strides) --------
__global__ void transpose_cvt(const float* __restrict__ src, long long srcZ,
                              __bf16* __restrict__ dst, int zmod,
                              long long dstZa, long long dstZb, int R, int C,
                              int dstLd) {
  __shared__ float t[32][33];
  int r0 = blockIdx.y * 32, c0 = blockIdx.x * 32;
  int z = blockIdx.z;
  src += (size_t)z * srcZ;
  dst += (size_t)(z / zmod) * dstZb + (size_t)(z % zmod) * dstZa;
  int tx = threadIdx.x, ty = threadIdx.y;
#pragma unroll
  for (int i = 0; i < 4; i++) {
    int r = r0 + ty + i * 8;
    t[ty + i * 8][tx] = src[(size_t)r * C + c0 + tx];
  }
  __syncthreads();
#pragma unroll
  for (int i = 0; i < 4; i++) {
    int c = c0 + ty + i * 8;
    dst[(size_t)c * dstLd + r0 + tx] = (__bf16)t[tx][ty + i * 8];
  }
}

__global__ void cvt_kernel(const float* __restrict__ s, __bf16* __restrict__ d,
                           int n) {
  for (int i = blockIdx.x * 256 + threadIdx.x; i < n; i += gridDim.x * 256)
    d[i] = (__bf16)s[i];
}

// ---------------- concat biases for all layers ---------------------------
__global__ void bias_all(const float* __restrict__ a,
                         const float* __restrict__ b,
                         const float* __restrict__ c, float* __restrict__ dst) {
  int i = blockIdx.x * 256 + threadIdx.x;
  if (i >= LNUM * 3 * D) return;
  int l = i / (3 * D), r = i % (3 * D);
  int w = r / D, d = r % D;
  const float* src = w == 0 ? a : (w == 1 ? b : c);
  dst[i] = src[l * D + d];
}

// ---------------- no-LDS flash attention ---------------------------------
// Block: 4 waves x 16 Q-rows. K-frags and V^T-frags direct from global.
// Only P round-trips through a wave-private LDS slab. Zero barriers.
#define P_LD 72
__global__ __launch_bounds__(256) void attn_nolds(
    const __bf16* __restrict__ qk, const __bf16* __restrict__ vT,
    __bf16* __restrict__ obf) {
  __shared__ __bf16 Pb[4][16 * P_LD];  // 2304 B per wave
  int q0 = blockIdx.x * 64, hh = blockIdx.y, b = blockIdx.z;
  int tid = threadIdx.x, lane = tid & 63, wv = tid >> 6;
  int col = lane & 15, half = lane >> 4;
  const float scale = 0.125f;  // HD^-0.5
  __bf16* P = &Pb[wv][0];

  const __bf16* qp =
      qk + (size_t)(b * S + q0 + wv * 16 + col) * 2048 + hh * HD;
  bf16x8 qf0 = *(const bf16x8*)(qp + half * 8);
  bf16x8 qf1 = *(const bf16x8*)(qp + 32 + half * 8);
  const __bf16* kbase = qk + (size_t)(b * S) * 2048 + 1024 + hh * HD;
  const __bf16* vbase = vT + (size_t)(hh * HD) * TOK + b * S;

  fx4 Oacc[4] = {};
  float m_i[4] = {-1e30f, -1e30f, -1e30f, -1e30f};
  float l_i[4] = {0.f, 0.f, 0.f, 0.f};

  for (int t0 = 0; t0 < S; t0 += 64) {
    // S = Q @ K^T, K-frags from global (16B contiguous per lane)
    fx4 sacc[4] = {};
#pragma unroll
    for (int n = 0; n < 4; n++) {
      const __bf16* kp = kbase + (size_t)(t0 + n * 16 + col) * 2048;
      bf16x8 b0 = *(const bf16x8*)(kp + half * 8);
      bf16x8 b1 = *(const bf16x8*)(kp + 32 + half * 8);
      sacc[n] =
          __builtin_amdgcn_mfma_f32_16x16x32_bf16(qf0, b0, sacc[n], 0, 0, 0);
      sacc[n] =
          __builtin_amdgcn_mfma_f32_16x16x32_bf16(qf1, b1, sacc[n], 0, 0, 0);
    }
    // online softmax (wave-local)
#pragma unroll
    for (int r = 0; r < 4; r++) {
      float mx =
          fmaxf(fmaxf(sacc[0][r], sacc[1][r]), fmaxf(sacc[2][r], sacc[3][r]));
#pragma unroll
      for (int msk = 1; msk < 16; msk <<= 1)
        mx = fmaxf(mx, __shfl_xor(mx, msk));
      float nm = fmaxf(m_i[r], mx * scale);
      float alpha = __expf(m_i[r] - nm);
      m_i[r] = nm;
      l_i[r] *= alpha;
#pragma unroll
      for (int n = 0; n < 4; n++) Oacc[n][r] *= alpha;
      float part = 0.f;
      int prow = (half * 4 + r) * P_LD;
#pragma unroll
      for (int n = 0; n < 4; n++) {
        float p = __expf(sacc[n][r] * scale - nm);
        part += p;
        P[prow + n * 16 + col] = (__bf16)p;
      }
#pragma unroll
      for (int msk = 1; msk < 16; msk <<= 1) part += __shfl_xor(part, msk);
      l_i[r] += part;
    }
    // O += P @ V, V^T-frags from global (16B contiguous per lane)
#pragma unroll
    for (int k0 = 0; k0 < 2; k0++) {
      bf16x8 af = *(const bf16x8*)(P + col * P_LD + k0 * 32 + half * 8);
#pragma unroll
      for (int n = 0; n < 4; n++) {
        bf16x8 bv = *(const bf16x8*)(vbase + (size_t)(n * 16 + col) * TOK + t0 +
                                     k0 * 32 + half * 8);
        Oacc[n] =
            __builtin_amdgcn_mfma_f32_16x16x32_bf16(af, bv, Oacc[n], 0, 0, 0);
      }
    }
  }
#pragma unroll
  for (int r = 0; r < 4; r++) {
    float inv = 1.f / l_i[r];
    int row = q0 + wv * 16 + half * 4 + r;
    __bf16* op = obf + (size_t)(b * S + row) * D + hh * HD;
#pragma unroll
    for (int n = 0; n < 4; n++) op[n * 16 + col] = (__bf16)(Oacc[n][r] * inv);
  }
}

// ---------------- final head: last token only ----------------
__global__ __launch_bounds__(256) void final_kernel(
    const float* __restrict__ h, const float* __restrict__ tg,
    const float* __restrict__ tb, const float* __restrict__ dg,
    const float* __restrict__ db, const float* __restrict__ ow,
    const float* __restrict__ ob, float* __restrict__ out) {
  int b = blockIdx.x;
  int tid = threadIdx.x;
  __shared__ float scratch[4];
  __shared__ float yf[D];
  const float* p = h + ((size_t)(b * S + (S - 1))) * D;
  float x[4];
  float s = 0.f, sq = 0.f;
#pragma unroll
  for (int i = 0; i < 4; i++) {
    x[i] = p[tid + i * 256];
    s += x[i];
    sq += x[i] * x[i];
  }
  s = block_reduce_sum256(s, scratch);
  sq = block_reduce_sum256(sq, scratch);
  float mean = s * (1.f / D);
  float inv = rsqrtf(sq * (1.f / D) - mean * mean + EPS);
  float y[4];
  s = 0.f;
  sq = 0.f;
#pragma unroll
  for (int i = 0; i < 4; i++) {
    int d = tid + i * 256;
    y[i] = (x[i] - mean) * inv * tg[d] + tb[d];
    s += y[i];
    sq += y[i] * y[i];
  }
  s = block_reduce_sum256(s, scratch);
  sq = block_reduce_sum256(sq, scratch);
  float mean2 = s * (1.f / D);
  float inv2 = rsqrtf(sq * (1.f / D) - mean2 * mean2 + EPS);
#pragma unroll
  for (int i = 0; i < 4; i++) {
    int d = tid + i * 256;
    yf[d] = (y[i] - mean2) * inv2 * dg[d] + db[d];
  }
  __syncthreads();
  for (int oo = 0; oo < NOUT; oo++) {
    float part = 0.f;
    for (int d = tid; d < D; d += 256) part += yf[d] * ow[(size_t)oo * D + d];
    part = block_reduce_sum256(part, scratch);
    if (tid == 0) out[b * NOUT + oo] = part + ob[oo];
  }
}

extern "C" void kernel_launch(void* const* d_in, const int* in_sizes, int n_in,
                              void* d_out, int out_size, void* d_ws,
                              size_t ws_size, hipStream_t stream) {
  const float* x = (const float*)d_in[0];
  const float* ln1_g = (const float*)d_in[1];
  const float* ln1_b = (const float*)d_in[2];
  const float* qw = (const float*)d_in[3];
  const float* qb_ = (const float*)d_in[4];
  const float* kw = (const float*)d_in[5];
  const float* kb_ = (const float*)d_in[6];
  const float* vw = (const float*)d_in[7];
  const float* vb_ = (const float*)d_in[8];
  const float* ow = (const float*)d_in[9];
  const float* ob = (const float*)d_in[10];
  const float* ln2_g = (const float*)d_in[11];
  const float* ln2_b = (const float*)d_in[12];
  const float* selw = (const float*)d_in[13];
  const float* w1 = (const float*)d_in[14];
  const float* w2 = (const float*)d_in[15];
  const float* lntg = (const float*)d_in[16];
  const float* lntb = (const float*)d_in[17];
  const float* lndg = (const float*)d_in[18];
  const float* lndb = (const float*)d_in[19];
  const float* inw = (const float*)d_in[20];
  const float* inb = (const float*)d_in[21];
  const float* outw = (const float*)d_in[22];
  const float* outb = (const float*)d_in[23];
  float* out = (float*)d_out;

  // ---- workspace layout (~76 MB) ----
  float* h = (float*)d_ws;                          // TOK*D f32
  float* gm = h + (size_t)TOK * D;                  // TOK*E
  float* qkvbias = gm + (size_t)TOK * E;            // L*3*D
  __bf16* xnb = (__bf16*)(qkvbias + LNUM * 3 * D);  // TOK*D
  __bf16* qkbf = xnb + (size_t)TOK * D;             // TOK*2048 (q|k)
  __bf16* vTb = qkbf + (size_t)TOK * 2048;          // D*TOK (v transposed)
  __bf16* obf = vTb + (size_t)D * TOK;              // TOK*D
  __bf16* qkvt = obf + (size_t)TOK * D;             // L*3*D*D
  __bf16* owt = qkvt + (size_t)LNUM * 3 * D * D;    // L*D*D
  __bf16* w1t = owt + (size_t)LNUM * D * D;         // L*E*EH*D
  __bf16* w2t = w1t + (size_t)LNUM * E * EH * D;    // L*D*E*EH
  __bf16* midb = qkbf;  // alias: q|k dead after attn; [TOK][2048]

  // ---- weight prep, all layers ----
  transpose_cvt<<<dim3(32, 32, LNUM), dim3(32, 8), 0, stream>>>(
      qw, (long long)D * D, qkvt, 1024, (long long)3 * D * D, 0, D, D, D);
  transpose_cvt<<<dim3(32, 32, LNUM), dim3(32, 8), 0, stream>>>(
      kw, (long long)D * D, qkvt + (size_t)D * D, 1024, (long long)3 * D * D, 0,
      D, D, D);
  transpose_cvt<<<dim3(32, 32, LNUM), dim3(32, 8), 0, stream>>>(
      vw, (long long)D * D, qkvt + (size_t)2 * D * D, 1024,
      (long long)3 * D * D, 0, D, D, D);
  cvt_kernel<<<1024, 256, 0, stream>>>(ow, owt, LNUM * D * D);
  transpose_cvt<<<dim3(EH / 32, D / 32, LNUM * E), dim3(32, 8), 0, stream>>>(
      w1, (long long)D * EH, w1t, 1024, (long long)EH * D, 0, D, EH, D);
  transpose_cvt<<<dim3(D / 32, EH / 32, LNUM * E), dim3(32, 8), 0, stream>>>(
      w2, (long long)EH * D, w2t, E, EH, (long long)D * E * EH, EH, D, E * EH);
  bias_all<<<(LNUM * 3 * D + 255) / 256, 256, 0, stream>>>(qb_, kb_, vb_,
                                                           qkvbias);

  gemm_kernel<<<dim3(D / 64, TOK / 64), 256, 0, stream>>>(x, inw, inb, h, TOK,
                                                          D, DIN);
  for (int l = 0; l < LNUM; l++) {
    ln_bf_kernel<<<TOK, 256, 0, stream>>>(h, ln1_g + l * D, ln1_b + l * D, xnb);
    // qkv folded: N=3072; q,k -> qkbf[token][2048] (+RoPE), v -> vT[d][token]
    mfma_gemm<4><<<dim3(3072 / 128, TOK / 64), 256, 0, stream>>>(
        xnb, D, qkvt + (size_t)l * 3 * D * D, qkvbias + l * 3 * D, nullptr,
        qkbf, 2048, vTb, nullptr, D, 0, 0, 1);
    attn_nolds<<<dim3(S / 64, H, B), 256, 0, stream>>>(qkbf, vTb, obf);
    // h += o @ ow^T + ob
    mfma_gemm<2><<<dim3(D / 64, TOK / 64), 256, 0, stream>>>(
        obf, D, owt + (size_t)l * D * D, ob + l * D, h, nullptr, D, nullptr,
        nullptr, D, 1, 0, 0);
    ln_gate_kernel<<<TOK, 256, 0, stream>>>(h, ln2_g + l * D, ln2_b + l * D,
                                            selw + (size_t)l * D * E, xnb, gm);
    // w1 folded: mid[t][e*EH+eh] = relu(xn @ w1cat) * gate[t][e]
    mfma_gemm<4><<<dim3(2048 / 128, TOK / 64), 256, 0, stream>>>(
        xnb, D, w1t + (size_t)l * E * EH * D, nullptr, nullptr, midb, 2048,
        nullptr, gm, D, 0, 1, 0);
    // h += mid @ w2stacked (K = 2048)
    mfma_gemm<2><<<dim3(D / 64, TOK / 64), 256, 0, stream>>>(
        midb, 2048, w2t + (size_t)l * D * E * EH, nullptr, h, nullptr, D,
        nullptr, nullptr, 2048, 1, 0, 0);
  }
  final_kernel<<<B, 256, 0, stream>>>(h, lntg, lntb, lndg, lndb, outw, outb,
                                      out);
}

// Round 8
// 668.593 us; speedup vs baseline: 1.1603x; 1.1603x over previous
//
#include <hip/hip_runtime.h>

// MoEUT time-series decoder, round 8.
// - attn_dbuf: flash attention with double-buffered async global->LDS K/V
//   staging (XOR-swizzled, conflict-free b128 reads), ONE barrier per
//   tile-iter, wave-owns-16-Q-rows (no cross-wave merge), XCD-aware grid
//   (x = head*batch so same-head blocks share an XCD's L2).
// - GEMMs unchanged from round 7 (dbuf 64xBN, folded QKV/w1/w2, vT epilogue).

#define LNUM 3
#define D 1024
#define H 16
#define HD 64
#define E 8
#define EH 256
#define B 2
#define S 1024
#define DIN 32
#define NOUT 8
#define EPS 1e-5f
#define TOK (B * S)

typedef __bf16 bf16x8 __attribute__((ext_vector_type(8)));
typedef __bf16 bf16x4 __attribute__((ext_vector_type(4)));
typedef float fx4 __attribute__((ext_vector_type(4)));

// ---------------- reductions ----------------
__device__ inline float block_reduce_sum256(float v, float* scratch) {
  int lane = threadIdx.x & 63, wv = threadIdx.x >> 6;
#pragma unroll
  for (int off = 32; off; off >>= 1) v += __shfl_down(v, off);
  __syncthreads();
  if (lane == 0) scratch[wv] = v;
  __syncthreads();
  return scratch[0] + scratch[1] + scratch[2] + scratch[3];
}

// ---------------- LayerNorm -> bf16 ----------------
__global__ __launch_bounds__(256) void ln_bf_kernel(
    const float* __restrict__ in, const float* __restrict__ g,
    const float* __restrict__ bta, __bf16* __restrict__ outb) {
  int token = blockIdx.x;
  int tid = threadIdx.x;
  const float* p = in + (size_t)token * D;
  __shared__ float scratch[4];
  float x[4];
  float s = 0.f, sq = 0.f;
#pragma unroll
  for (int i = 0; i < 4; i++) {
    x[i] = p[tid + i * 256];
    s += x[i];
    sq += x[i] * x[i];
  }
  s = block_reduce_sum256(s, scratch);
  sq = block_reduce_sum256(sq, scratch);
  float mean = s * (1.f / D);
  float inv = rsqrtf(sq * (1.f / D) - mean * mean + EPS);
  __bf16* obp = outb + (size_t)token * D;
#pragma unroll
  for (int i = 0; i < 4; i++) {
    int d = tid + i * 256;
    obp[d] = (__bf16)((x[i] - mean) * inv * g[d] + bta[d]);
  }
}

// ---------------- LayerNorm + sigmoid gate top-2 (fused) ----------------
__global__ __launch_bounds__(256) void ln_gate_kernel(
    const float* __restrict__ in, const float* __restrict__ g,
    const float* __restrict__ bta, const float* __restrict__ selw,
    __bf16* __restrict__ outb, float* __restrict__ gm) {
  int token = blockIdx.x;
  int tid = threadIdx.x;
  const float* p = in + (size_t)token * D;
  __shared__ float scratch[4];
  float x[4];
  float s = 0.f, sq = 0.f;
#pragma unroll
  for (int i = 0; i < 4; i++) {
    x[i] = p[tid + i * 256];
    s += x[i];
    sq += x[i] * x[i];
  }
  s = block_reduce_sum256(s, scratch);
  sq = block_reduce_sum256(sq, scratch);
  float mean = s * (1.f / D);
  float inv = rsqrtf(sq * (1.f / D) - mean * mean + EPS);
  __bf16* obp = outb + (size_t)token * D;
  float ge[E];
#pragma unroll
  for (int e = 0; e < E; e++) ge[e] = 0.f;
#pragma unroll
  for (int i = 0; i < 4; i++) {
    int d = tid + i * 256;
    float y = (x[i] - mean) * inv * g[d] + bta[d];
    obp[d] = (__bf16)y;
#pragma unroll
    for (int e = 0; e < E; e++) ge[e] += y * selw[d * E + e];
  }
  __shared__ float red[4][E];
  int lane = tid & 63, wv = tid >> 6;
#pragma unroll
  for (int e = 0; e < E; e++) {
    float vv = ge[e];
#pragma unroll
    for (int off = 32; off; off >>= 1) vv += __shfl_down(vv, off);
    if (lane == 0) red[wv][e] = vv;
  }
  __syncthreads();
  if (tid == 0) {
    float gg[E];
    for (int e = 0; e < E; e++) {
      float sv = red[0][e] + red[1][e] + red[2][e] + red[3][e];
      gg[e] = 1.f / (1.f + __expf(-sv));
    }
    int i0 = 0;
    for (int e = 1; e < E; e++)
      if (gg[e] > gg[i0]) i0 = e;
    int i1 = -1;
    for (int e = 0; e < E; e++) {
      if (e == i0) continue;
      if (i1 < 0 || gg[e] > gg[i1]) i1 = e;
    }
    float mm[E];
    for (int e = 0; e < E; e++) mm[e] = 0.f;
    mm[i0] = gg[i0];
    mm[i1] = gg[i1];
    for (int e = 0; e < E; e++) gm[(size_t)token * E + e] = mm[e];
  }
}

// ---------------- fp32 tiled GEMM (input projection, K=32) ----------
#define BM 64
#define BKT 16
__global__ __launch_bounds__(256) void gemm_kernel(
    const float* __restrict__ A, const float* __restrict__ Bw,
    const float* __restrict__ bias, float* __restrict__ C, int M, int N,
    int Kd) {
  __shared__ float As[BKT][BM + 1];
  __shared__ float Bs[BKT][BM + 1];
  int bm = blockIdx.y * BM, bn = blockIdx.x * BM;
  int tid = threadIdx.x;
  int tx = tid & 15, ty = tid >> 4;
  float acc[4][4] = {};
  for (int k0 = 0; k0 < Kd; k0 += BKT) {
#pragma unroll
    for (int j = 0; j < 4; j++) {
      int i = tid + j * 256;
      int r = i >> 4, c = i & 15;
      As[c][r] = A[(size_t)(bm + r) * Kd + k0 + c];
    }
#pragma unroll
    for (int j = 0; j < 4; j++) {
      int i = tid + j * 256;
      int n = i >> 4, c = i & 15;
      Bs[c][n] = Bw[(size_t)(bn + n) * Kd + k0 + c];
    }
    __syncthreads();
#pragma unroll
    for (int kk = 0; kk < BKT; kk++) {
      float a[4], bb[4];
#pragma unroll
      for (int i2 = 0; i2 < 4; i2++) a[i2] = As[kk][ty * 4 + i2];
#pragma unroll
      for (int i2 = 0; i2 < 4; i2++) bb[i2] = Bs[kk][tx * 4 + i2];
#pragma unroll
      for (int i2 = 0; i2 < 4; i2++)
#pragma unroll
        for (int j2 = 0; j2 < 4; j2++) acc[i2][j2] += a[i2] * bb[j2];
    }
    __syncthreads();
  }
#pragma unroll
  for (int i2 = 0; i2 < 4; i2++) {
    int row = bm + ty * 4 + i2;
#pragma unroll
    for (int j2 = 0; j2 < 4; j2++) {
      int col = bn + tx * 4 + j2;
      C[(size_t)row * N + col] = acc[i2][j2] + bias[col];
    }
  }
}

// ---------------- bf16 MFMA GEMM, 64xBN, BK=32, dbuf, 1 barrier/iter -----
template <int NI>
__global__ __launch_bounds__(256) void mfma_gemm(
    const __bf16* __restrict__ A, int lda, const __bf16* __restrict__ Bt,
    const float* __restrict__ bias, float* __restrict__ C,
    __bf16* __restrict__ Cbf, int ldc, __bf16* __restrict__ vT,
    const float* __restrict__ gateScale, int K, int accum, int relu,
    int rope) {
  constexpr int BN = NI * 32;
  __shared__ __bf16 As[2][64 * 32];
  __shared__ __bf16 Bs[2][BN * 32];
  int bm = blockIdx.y * 64, bn = blockIdx.x * BN;
  int tid = threadIdx.x, lane = tid & 63, wv = tid >> 6;
  int wr = wv >> 1, wc = wv & 1;
  int half = lane >> 4, mrow = lane & 15;
  const __bf16* Ab = A + (size_t)bm * lda;
  const __bf16* Bb = Bt + (size_t)bn * K;
  fx4 acc[2][NI] = {};
  int aslot[2], bslot[NI];
#pragma unroll
  for (int i = 0; i < 2; i++) {
    int row = wr * 32 + i * 16 + mrow;
    aslot[i] = row * 4 + (half ^ ((row >> 1) & 3));
  }
#pragma unroll
  for (int j = 0; j < NI; j++) {
    int row = wc * (NI * 16) + j * 16 + mrow;
    bslot[j] = row * 4 + (half ^ ((row >> 1) & 3));
  }
  int rowa = tid >> 2, kca = (((tid & 3) ^ ((rowa >> 1) & 3)) << 3);

  auto stage = [&](int buf, int k0) {
    __builtin_amdgcn_global_load_lds(
        (const __attribute__((address_space(1))) void*)(Ab +
                                                        (size_t)rowa * lda +
                                                        k0 + kca),
        (__attribute__((address_space(3))) void*)(&As[buf][tid * 8]), 16, 0, 0);
#pragma unroll
    for (int it = 0; it < NI / 2; it++) {
      int c = tid + it * 256;
      int row = c >> 2;
      int kc = (((c & 3) ^ ((row >> 1) & 3)) << 3);
      __builtin_amdgcn_global_load_lds(
          (const __attribute__((address_space(1))) void*)(Bb + (size_t)row * K +
                                                          k0 + kc),
          (__attribute__((address_space(3))) void*)(&Bs[buf][c * 8]), 16, 0, 0);
    }
  };
  stage(0, 0);
  for (int k0 = 0; k0 < K; k0 += 32) {
    int cur = (k0 >> 5) & 1;
    __syncthreads();
    if (k0 + 32 < K) stage(cur ^ 1, k0 + 32);
    bf16x8 af[2], bfr[NI];
#pragma unroll
    for (int i = 0; i < 2; i++)
      af[i] = *(const bf16x8*)(&As[cur][aslot[i] * 8]);
#pragma unroll
    for (int j = 0; j < NI; j++)
      bfr[j] = *(const bf16x8*)(&Bs[cur][bslot[j] * 8]);
#pragma unroll
    for (int i = 0; i < 2; i++)
#pragma unroll
      for (int j = 0; j < NI; j++)
        acc[i][j] = __builtin_amdgcn_mfma_f32_16x16x32_bf16(af[i], bfr[j],
                                                            acc[i][j], 0, 0, 0);
  }
  if (vT && bn >= 2048) {
#pragma unroll
    for (int i = 0; i < 2; i++) {
      int row0 = bm + wr * 32 + i * 16 + half * 4;
#pragma unroll
      for (int j = 0; j < NI; j++) {
        int col = bn + wc * (NI * 16) + j * 16 + mrow;
        float bb = bias ? bias[col] : 0.f;
        bf16x4 pk;
#pragma unroll
        for (int r = 0; r < 4; r++) pk[r] = (__bf16)(acc[i][j][r] + bb);
        *(bf16x4*)(vT + (size_t)(col - 2048) * TOK + row0) = pk;
      }
    }
    return;
  }
#pragma unroll
  for (int i = 0; i < 2; i++) {
#pragma unroll
    for (int r = 0; r < 4; r++) {
      int row = bm + wr * 32 + i * 16 + half * 4 + r;
      float vv[NI];
#pragma unroll
      for (int j = 0; j < NI; j++) {
        int col = bn + wc * (NI * 16) + j * 16 + mrow;
        float val = acc[i][j][r];
        if (bias) val += bias[col];
        if (relu) val = fmaxf(val, 0.f);
        if (gateScale) val *= gateScale[(size_t)row * E + (col >> 8)];
        vv[j] = val;
      }
      if (rope && NI == 4) {
        int spos = row & (S - 1);
#pragma unroll
        for (int jj = 0; jj < 2; jj++) {
          int hd = jj * 16 + mrow;  // 0..31
          float invf = exp2f(hd * -0.4152410118609825f);
          float ang = (float)spos * invf;
          float sn, cs;
          __sincosf(ang, &sn, &cs);
          float a0 = vv[jj], a1 = vv[jj + 2];
          vv[jj] = a0 * cs - a1 * sn;
          vv[jj + 2] = a1 * cs + a0 * sn;
        }
      }
#pragma unroll
      for (int j = 0; j < NI; j++) {
        int col = bn + wc * (NI * 16) + j * 16 + mrow;
        size_t addr = (size_t)row * ldc + col;
        if (Cbf)
          Cbf[addr] = (__bf16)vv[j];
        else if (accum)
          C[addr] += vv[j];
        else
          C[addr] = vv[j];
      }
    }
  }
}

// ---------------- fp32 -> bf16 transpose+convert (z-split strides) --------
__global__ void transpose_cvt(const float* __restrict__ src, long long srcZ,
                              __bf16* __restrict__ dst, int zmod,
                              long long dstZa, long long dstZb, int R, int C,
                              int dstLd) {
  __shared__ float t[32][33];
  int r0 = blockIdx.y * 32, c0 = blockIdx.x * 32;
  int z = blockIdx.z;
  src += (size_t)z * srcZ;
  dst += (size_t)(z / zmod) * dstZb + (size_t)(z % zmod) * dstZa;
  int tx = threadIdx.x, ty = threadIdx.y;
#pragma unroll
  for (int i = 0; i < 4; i++) {
    int r = r0 + ty + i * 8;
    t[ty + i * 8][tx] = src[(size_t)r * C + c0 + tx];
  }
  __syncthreads();
#pragma unroll
  for (int i = 0; i < 4; i++) {
    int c = c0 + ty + i * 8;
    dst[(size_t)c * dstLd + r0 + tx] = (__bf16)t[tx][ty + i * 8];
  }
}

__global__ void cvt_kernel(const float* __restrict__ s, __bf16* __restrict__ d,
                           int n) {
  for (int i = blockIdx.x * 256 + threadIdx.x; i < n; i += gridDim.x * 256)
    d[i] = (__bf16)s[i];
}

// ---------------- concat biases for all layers ---------------------------
__global__ void bias_all(const float* __restrict__ a,
                         const float* __restrict__ b,
                         const float* __restrict__ c, float* __restrict__ dst) {
  int i = blockIdx.x * 256 + threadIdx.x;
  if (i >= LNUM * 3 * D) return;
  int l = i / (3 * D), r = i % (3 * D);
  int w = r / D, d = r % D;
  const float* src = w == 0 ? a : (w == 1 ? b : c);
  dst[i] = src[l * D + d];
}

// ---------------- dbuf async-staged flash attention ----------------------
// Grid: x = head*2+batch (same (h,b) -> same XCD), y = q-tile.
// Block: 4 waves x 16 Q-rows over all S. K/V tiles (64 keys) double-buffered
// in LDS via global_load_lds with XOR chunk swizzle; 1 barrier per iter.
#define P_LD 72
__global__ __launch_bounds__(256) void attn_dbuf(
    const __bf16* __restrict__ qk, const __bf16* __restrict__ vT,
    __bf16* __restrict__ obf) {
  __shared__ __bf16 Kt[2][64 * 64];    // 16 KB
  __shared__ __bf16 Vt[2][64 * 64];    // 16 KB
  __shared__ __bf16 Pb[4][16 * P_LD];  // 9 KB
  int hb = blockIdx.x, q0 = blockIdx.y * 64;
  int hh = hb >> 1, b = hb & 1;
  int tid = threadIdx.x, lane = tid & 63, wv = tid >> 6;
  int col = lane & 15, half = lane >> 4;
  const float scale = 0.125f;  // HD^-0.5
  __bf16* P = &Pb[wv][0];

  const __bf16* qp = qk + (size_t)(b * S + q0 + wv * 16 + col) * 2048 + hh * HD;
  bf16x8 qf0 = *(const bf16x8*)(qp + half * 8);
  bf16x8 qf1 = *(const bf16x8*)(qp + 32 + half * 8);
  const __bf16* kbase = qk + (size_t)(b * S) * 2048 + 1024 + hh * HD;
  const __bf16* vbase = vT + (size_t)(hh * HD) * TOK + b * S;

  // staging addresses: chunk c (0..511), row = c>>3, slot = c&7,
  // global chunk g = slot ^ (row&7)
  int srow = tid >> 3, sslot = tid & 7;
  int sg = sslot ^ (srow & 7);
  int srow2 = (tid + 256) >> 3, sslot2 = tid & 7;
  int sg2 = sslot2 ^ (srow2 & 7);

  auto stage = [&](int buf, int t0) {
    __builtin_amdgcn_global_load_lds(
        (const __attribute__((address_space(1))) void*)(kbase +
                                                        (size_t)(t0 + srow) *
                                                            2048 +
                                                        sg * 8),
        (__attribute__((address_space(3))) void*)(&Kt[buf][tid * 8]), 16, 0, 0);
    __builtin_amdgcn_global_load_lds(
        (const __attribute__((address_space(1))) void*)(kbase +
                                                        (size_t)(t0 + srow2) *
                                                            2048 +
                                                        sg2 * 8),
        (__attribute__((address_space(3))) void*)(&Kt[buf][(tid + 256) * 8]),
        16, 0, 0);
    __builtin_amdgcn_global_load_lds(
        (const __attribute__((address_space(1))) void*)(vbase +
                                                        (size_t)srow * TOK +
                                                        t0 + sg * 8),
        (__attribute__((address_space(3))) void*)(&Vt[buf][tid * 8]), 16, 0, 0);
    __builtin_amdgcn_global_load_lds(
        (const __attribute__((address_space(1))) void*)(vbase +
                                                        (size_t)srow2 * TOK +
                                                        t0 + sg2 * 8),
        (__attribute__((address_space(3))) void*)(&Vt[buf][(tid + 256) * 8]),
        16, 0, 0);
  };

  fx4 Oacc[4] = {};
  float m_i[4] = {-1e30f, -1e30f, -1e30f, -1e30f};
  float l_i[4] = {0.f, 0.f, 0.f, 0.f};

  stage(0, 0);
  for (int t0 = 0; t0 < S; t0 += 64) {
    int cur = (t0 >> 6) & 1;
    __syncthreads();  // drains DMA for `cur`; protects prior reads of cur^1
    if (t0 + 64 < S) stage(cur ^ 1, t0 + 64);
    // S = Q @ K^T
    fx4 sacc[4] = {};
#pragma unroll
    for (int n = 0; n < 4; n++) {
      int rowk = n * 16 + col;
      const __bf16* kp = &Kt[cur][rowk * 64];
      bf16x8 b0 = *(const bf16x8*)(kp + ((half ^ (rowk & 7)) << 3));
      bf16x8 b1 = *(const bf16x8*)(kp + (((4 + half) ^ (rowk & 7)) << 3));
      sacc[n] =
          __builtin_amdgcn_mfma_f32_16x16x32_bf16(qf0, b0, sacc[n], 0, 0, 0);
      sacc[n] =
          __builtin_amdgcn_mfma_f32_16x16x32_bf16(qf1, b1, sacc[n], 0, 0, 0);
    }
    // online softmax (wave-local)
#pragma unroll
    for (int r = 0; r < 4; r++) {
      float mx =
          fmaxf(fmaxf(sacc[0][r], sacc[1][r]), fmaxf(sacc[2][r], sacc[3][r]));
#pragma unroll
      for (int msk = 1; msk < 16; msk <<= 1)
        mx = fmaxf(mx, __shfl_xor(mx, msk));
      float nm = fmaxf(m_i[r], mx * scale);
      float alpha = __expf(m_i[r] - nm);
      m_i[r] = nm;
      l_i[r] *= alpha;
#pragma unroll
      for (int n = 0; n < 4; n++) Oacc[n][r] *= alpha;
      float part = 0.f;
      int prow = (half * 4 + r) * P_LD;
#pragma unroll
      for (int n = 0; n < 4; n++) {
        float p = __expf(sacc[n][r] * scale - nm);
        part += p;
        P[prow + n * 16 + col] = (__bf16)p;
      }
#pragma unroll
      for (int msk = 1; msk < 16; msk <<= 1) part += __shfl_xor(part, msk);
      l_i[r] += part;
    }
    // O += P @ V
#pragma unroll
    for (int k0 = 0; k0 < 2; k0++) {
      bf16x8 af = *(const bf16x8*)(P + col * P_LD + k0 * 32 + half * 8);
#pragma unroll
      for (int n = 0; n < 4; n++) {
        int rowd = n * 16 + col;
        int g = k0 * 4 + half;
        bf16x8 bv =
            *(const bf16x8*)(&Vt[cur][rowd * 64 + ((g ^ (rowd & 7)) << 3)]);
        Oacc[n] =
            __builtin_amdgcn_mfma_f32_16x16x32_bf16(af, bv, Oacc[n], 0, 0, 0);
      }
    }
  }
#pragma unroll
  for (int r = 0; r < 4; r++) {
    float inv = 1.f / l_i[r];
    int row = q0 + wv * 16 + half * 4 + r;
    __bf16* op = obf + (size_t)(b * S + row) * D + hh * HD;
#pragma unroll
    for (int n = 0; n < 4; n++) op[n * 16 + col] = (__bf16)(Oacc[n][r] * inv);
  }
}

// ---------------- final head: last token only ----------------
__global__ __launch_bounds__(256) void final_kernel(
    const float* __restrict__ h, const float* __restrict__ tg,
    const float* __restrict__ tb, const float* __restrict__ dg,
    const float* __restrict__ db, const float* __restrict__ ow,
    const float* __restrict__ ob, float* __restrict__ out) {
  int b = blockIdx.x;
  int tid = threadIdx.x;
  __shared__ float scratch[4];
  __shared__ float yf[D];
  const float* p = h + ((size_t)(b * S + (S - 1))) * D;
  float x[4];
  float s = 0.f, sq = 0.f;
#pragma unroll
  for (int i = 0; i < 4; i++) {
    x[i] = p[tid + i * 256];
    s += x[i];
    sq += x[i] * x[i];
  }
  s = block_reduce_sum256(s, scratch);
  sq = block_reduce_sum256(sq, scratch);
  float mean = s * (1.f / D);
  float inv = rsqrtf(sq * (1.f / D) - mean * mean + EPS);
  float y[4];
  s = 0.f;
  sq = 0.f;
#pragma unroll
  for (int i = 0; i < 4; i++) {
    int d = tid + i * 256;
    y[i] = (x[i] - mean) * inv * tg[d] + tb[d];
    s += y[i];
    sq += y[i] * y[i];
  }
  s = block_reduce_sum256(s, scratch);
  sq = block_reduce_sum256(sq, scratch);
  float mean2 = s * (1.f / D);
  float inv2 = rsqrtf(sq * (1.f / D) - mean2 * mean2 + EPS);
#pragma unroll
  for (int i = 0; i < 4; i++) {
    int d = tid + i * 256;
    yf[d] = (y[i] - mean2) * inv2 * dg[d] + db[d];
  }
  __syncthreads();
  for (int oo = 0; oo < NOUT; oo++) {
    float part = 0.f;
    for (int d = tid; d < D; d += 256) part += yf[d] * ow[(size_t)oo * D + d];
    part = block_reduce_sum256(part, scratch);
    if (tid == 0) out[b * NOUT + oo] = part + ob[oo];
  }
}

extern "C" void kernel_launch(void* const* d_in, const int* in_sizes, int n_in,
                              void* d_out, int out_size, void* d_ws,
                              size_t ws_size, hipStream_t stream) {
  const float* x = (const float*)d_in[0];
  const float* ln1_g = (const float*)d_in[1];
  const float* ln1_b = (const float*)d_in[2];
  const float* qw = (const float*)d_in[3];
  const float* qb_ = (const float*)d_in[4];
  const float* kw = (const float*)d_in[5];
  const float* kb_ = (const float*)d_in[6];
  const float* vw = (const float*)d_in[7];
  const float* vb_ = (const float*)d_in[8];
  const float* ow = (const float*)d_in[9];
  const float* ob = (const float*)d_in[10];
  const float* ln2_g = (const float*)d_in[11];
  const float* ln2_b = (const float*)d_in[12];
  const float* selw = (const float*)d_in[13];
  const float* w1 = (const float*)d_in[14];
  const float* w2 = (const float*)d_in[15];
  const float* lntg = (const float*)d_in[16];
  const float* lntb = (const float*)d_in[17];
  const float* lndg = (const float*)d_in[18];
  const float* lndb = (const float*)d_in[19];
  const float* inw = (const float*)d_in[20];
  const float* inb = (const float*)d_in[21];
  const float* outw = (const float*)d_in[22];
  const float* outb = (const float*)d_in[23];
  float* out = (float*)d_out;

  // ---- workspace layout (~76 MB) ----
  float* h = (float*)d_ws;                          // TOK*D f32
  float* gm = h + (size_t)TOK * D;                  // TOK*E
  float* qkvbias = gm + (size_t)TOK * E;            // L*3*D
  __bf16* xnb = (__bf16*)(qkvbias + LNUM * 3 * D);  // TOK*D
  __bf16* qkbf = xnb + (size_t)TOK * D;             // TOK*2048 (q|k)
  __bf16* vTb = qkbf + (size_t)TOK * 2048;          // D*TOK (v transposed)
  __bf16* obf = vTb + (size_t)D * TOK;              // TOK*D
  __bf16* qkvt = obf + (size_t)TOK * D;             // L*3*D*D
  __bf16* owt = qkvt + (size_t)LNUM * 3 * D * D;    // L*D*D
  __bf16* w1t = owt + (size_t)LNUM * D * D;         // L*E*EH*D
  __bf16* w2t = w1t + (size_t)LNUM * E * EH * D;    // L*D*E*EH
  __bf16* midb = qkbf;  // alias: q|k dead after attn; [TOK][2048]

  // ---- weight prep, all layers ----
  transpose_cvt<<<dim3(32, 32, LNUM), dim3(32, 8), 0, stream>>>(
      qw, (long long)D * D, qkvt, 1024, (long long)3 * D * D, 0, D, D, D);
  transpose_cvt<<<dim3(32, 32, LNUM), dim3(32, 8), 0, stream>>>(
      kw, (long long)D * D, qkvt + (size_t)D * D, 1024, (long long)3 * D * D, 0,
      D, D, D);
  transpose_cvt<<<dim3(32, 32, LNUM), dim3(32, 8), 0, stream>>>(
      vw, (long long)D * D, qkvt + (size_t)2 * D * D, 1024,
      (long long)3 * D * D, 0, D, D, D);
  cvt_kernel<<<1024, 256, 0, stream>>>(ow, owt, LNUM * D * D);
  transpose_cvt<<<dim3(EH / 32, D / 32, LNUM * E), dim3(32, 8), 0, stream>>>(
      w1, (long long)D * EH, w1t, 1024, (long long)EH * D, 0, D, EH, D);
  transpose_cvt<<<dim3(D / 32, EH / 32, LNUM * E), dim3(32, 8), 0, stream>>>(
      w2, (long long)EH * D, w2t, E, EH, (long long)D * E * EH, EH, D, E * EH);
  bias_all<<<(LNUM * 3 * D + 255) / 256, 256, 0, stream>>>(qb_, kb_, vb_,
                                                           qkvbias);

  gemm_kernel<<<dim3(D / 64, TOK / 64), 256, 0, stream>>>(x, inw, inb, h, TOK,
                                                          D, DIN);
  for (int l = 0; l < LNUM; l++) {
    ln_bf_kernel<<<TOK, 256, 0, stream>>>(h, ln1_g + l * D, ln1_b + l * D, xnb);
    // qkv folded: N=3072; q,k -> qkbf[token][2048] (+RoPE), v -> vT[d][token]
    mfma_gemm<4><<<dim3(3072 / 128, TOK / 64), 256, 0, stream>>>(
        xnb, D, qkvt + (size_t)l * 3 * D * D, qkvbias + l * 3 * D, nullptr,
        qkbf, 2048, vTb, nullptr, D, 0, 0, 1);
    attn_dbuf<<<dim3(H * B, S / 64), 256, 0, stream>>>(qkbf, vTb, obf);
    // h += o @ ow^T + ob
    mfma_gemm<2><<<dim3(D / 64, TOK / 64), 256, 0, stream>>>(
        obf, D, owt + (size_t)l * D * D, ob + l * D, h, nullptr, D, nullptr,
        nullptr, D, 1, 0, 0);
    ln_gate_kernel<<<TOK, 256, 0, stream>>>(h, ln2_g + l * D, ln2_b + l * D,
                                            selw + (size_t)l * D * E, xnb, gm);
    // w1 folded: mid[t][e*EH+eh] = relu(xn @ w1cat) * gate[t][e]
    mfma_gemm<4><<<dim3(2048 / 128, TOK / 64), 256, 0, stream>>>(
        xnb, D, w1t + (size_t)l * E * EH * D, nullptr, nullptr, midb, 2048,
        nullptr, gm, D, 0, 1, 0);
    // h += mid @ w2stacked (K = 2048)
    mfma_gemm<2><<<dim3(D / 64, TOK / 64), 256, 0, stream>>>(
        midb, 2048, w2t + (size_t)l * D * E * EH, nullptr, h, nullptr, D,
        nullptr, nullptr, 2048, 1, 0, 0);
  }
  final_kernel<<<B, 256, 0, stream>>>(h, lntg, lntb, lndg, lndb, outw, outb,
                                      out);
}